// Round 1
// baseline (185.862 us; speedup 1.0000x reference)
//
#include <hip/hip_runtime.h>

// Sampler reduces to row-wise argmax:
//   - temperature scale (T>0) is monotone -> argmax unchanged
//   - top-p/top-k never mask the rank-0 (max) token; all other tokens can
//     only go to -inf -> argmax unchanged
//   - softmax is monotone per row -> argmax(probs) == argmax(logits)
// So: out[row] = argmax(logits[row, :]) as int32, first-index tie-break
// (matches jnp.argmax semantics).

#define VOCAB 128000

__global__ __launch_bounds__(1024, 1) void argmax_rows(
    const float* __restrict__ logits, int* __restrict__ out) {
    const int row = blockIdx.x;
    const float4* __restrict__ rowp =
        reinterpret_cast<const float4*>(logits + (size_t)row * VOCAB);
    const int n4 = VOCAB / 4;  // 32000, evenly divisible

    float best = -3.402823466e+38f;
    int bestIdx = 0x7fffffff;

    // Per-thread scan: indices strictly increase within a thread, and we use
    // strict '>' -> the first (lowest-index) occurrence of the max is kept.
    for (int i = threadIdx.x; i < n4; i += blockDim.x) {
        float4 v = rowp[i];
        const int base = i << 2;
        if (v.x > best) { best = v.x; bestIdx = base; }
        if (v.y > best) { best = v.y; bestIdx = base + 1; }
        if (v.z > best) { best = v.z; bestIdx = base + 2; }
        if (v.w > best) { best = v.w; bestIdx = base + 3; }
    }

    // Wave-64 shuffle reduce; tie-break toward lower index.
    #pragma unroll
    for (int off = 32; off > 0; off >>= 1) {
        float ov = __shfl_down(best, off, 64);
        int   oi = __shfl_down(bestIdx, off, 64);
        if (ov > best || (ov == best && oi < bestIdx)) { best = ov; bestIdx = oi; }
    }

    // Cross-wave reduce via LDS (16 waves per 1024-thread block).
    __shared__ float s_val[16];
    __shared__ int   s_idx[16];
    const int lane = threadIdx.x & 63;
    const int wave = threadIdx.x >> 6;
    if (lane == 0) { s_val[wave] = best; s_idx[wave] = bestIdx; }
    __syncthreads();

    if (wave == 0) {
        const int nw = blockDim.x >> 6;
        float v  = (lane < nw) ? s_val[lane] : -3.402823466e+38f;
        int   ix = (lane < nw) ? s_idx[lane] : 0x7fffffff;
        #pragma unroll
        for (int off = 32; off > 0; off >>= 1) {
            float ov = __shfl_down(v, off, 64);
            int   oi = __shfl_down(ix, off, 64);
            if (ov > v || (ov == v && oi < ix)) { v = ov; ix = oi; }
        }
        if (lane == 0) out[row] = ix;
    }
}

extern "C" void kernel_launch(void* const* d_in, const int* in_sizes, int n_in,
                              void* d_out, int out_size, void* d_ws, size_t ws_size,
                              hipStream_t stream) {
    const float* logits = (const float*)d_in[0];
    int* out = (int*)d_out;
    const int batch = out_size;  // 256 rows, one int32 index each
    argmax_rows<<<batch, 1024, 0, stream>>>(logits, out);
}

// Round 2
// 184.646 us; speedup vs baseline: 1.0066x; 1.0066x over previous
//
#include <hip/hip_runtime.h>

// Sampler reduces to row-wise argmax (temperature>0 is monotone; top-p/top-k
// never mask the rank-0 token; softmax is monotone). out[row] = argmax(row),
// first-index tie-break (jnp.argmax semantics).
//
// 131 MB fp32 read, 1 KB write -> pure memory-bound. 256 rows -> 1 block/CU,
// 1024 thr (16 waves). Unroll x4 with 4 independent (best,idx) streams so 4
// float4 loads stay in flight per wave (no serial compare dependency).

#define VOCAB 128000
#define NT4   (VOCAB / 4)     // 32000 float4 per row
#define BLK   1024
#define NFULL (NT4 / (BLK * 4))  // 7 full x4 iterations (28672 float4)

#define NEG_INF (-3.402823466e+38f)

__device__ __forceinline__ void upd(float v, int idx, float& b, int& bi) {
    if (v > b) { b = v; bi = idx; }
}

__device__ __forceinline__ void upd4(const float4& v, int base, float& b, int& bi) {
    upd(v.x, base + 0, b, bi);
    upd(v.y, base + 1, b, bi);
    upd(v.z, base + 2, b, bi);
    upd(v.w, base + 3, b, bi);
}

__global__ __launch_bounds__(BLK, 1) void argmax_rows(
    const float* __restrict__ logits, int* __restrict__ out) {
    const int row = blockIdx.x;
    const int tid = threadIdx.x;
    const float4* __restrict__ rowp =
        reinterpret_cast<const float4*>(logits + (size_t)row * VOCAB);

    float b0 = NEG_INF, b1 = NEG_INF, b2 = NEG_INF, b3 = NEG_INF;
    int   i0 = 0x7fffffff, i1 = 0x7fffffff, i2 = 0x7fffffff, i3 = 0x7fffffff;

    int i = tid;
    #pragma unroll 1
    for (int it = 0; it < NFULL; ++it, i += 4 * BLK) {
        // 4 independent loads issued before any compare consumes them
        float4 v0 = rowp[i];
        float4 v1 = rowp[i + BLK];
        float4 v2 = rowp[i + 2 * BLK];
        float4 v3 = rowp[i + 3 * BLK];
        upd4(v0, (i) << 2,            b0, i0);
        upd4(v1, (i + BLK) << 2,      b1, i1);
        upd4(v2, (i + 2 * BLK) << 2,  b2, i2);
        upd4(v3, (i + 3 * BLK) << 2,  b3, i3);
    }
    // tail: float4 indices [28672, 32000)
    for (; i < NT4; i += BLK) {
        float4 v = rowp[i];
        upd4(v, i << 2, b0, i0);
    }

    // merge 4 streams; ties -> lower index (streams have disjoint index sets,
    // but equal values across streams need the index tie-break)
    float best = b0; int bestIdx = i0;
    if (b1 > best || (b1 == best && i1 < bestIdx)) { best = b1; bestIdx = i1; }
    if (b2 > best || (b2 == best && i2 < bestIdx)) { best = b2; bestIdx = i2; }
    if (b3 > best || (b3 == best && i3 < bestIdx)) { best = b3; bestIdx = i3; }

    // wave-64 shuffle reduce, tie-break toward lower index
    #pragma unroll
    for (int off = 32; off > 0; off >>= 1) {
        float ov = __shfl_down(best, off, 64);
        int   oi = __shfl_down(bestIdx, off, 64);
        if (ov > best || (ov == best && oi < bestIdx)) { best = ov; bestIdx = oi; }
    }

    // cross-wave reduce via LDS (16 waves)
    __shared__ float s_val[16];
    __shared__ int   s_idx[16];
    const int lane = tid & 63;
    const int wave = tid >> 6;
    if (lane == 0) { s_val[wave] = best; s_idx[wave] = bestIdx; }
    __syncthreads();

    if (wave == 0) {
        float v  = (lane < 16) ? s_val[lane] : NEG_INF;
        int   ix = (lane < 16) ? s_idx[lane] : 0x7fffffff;
        #pragma unroll
        for (int off = 8; off > 0; off >>= 1) {
            float ov = __shfl_down(v, off, 64);
            int   oi = __shfl_down(ix, off, 64);
            if (ov > v || (ov == v && oi < ix)) { v = ov; ix = oi; }
        }
        if (lane == 0) out[row] = ix;
    }
}

extern "C" void kernel_launch(void* const* d_in, const int* in_sizes, int n_in,
                              void* d_out, int out_size, void* d_ws, size_t ws_size,
                              hipStream_t stream) {
    const float* logits = (const float*)d_in[0];
    int* out = (int*)d_out;
    argmax_rows<<<out_size, BLK, 0, stream>>>(logits, out);
}